// Round 11
// baseline (406.531 us; speedup 1.0000x reference)
//
#include <hip/hip_runtime.h>
#include <hip/hip_bf16.h>

// R11: both GEMMs were latency-bound on exposed staging drains (stage ->
// barrier -> compute; MfmaUtil 10%, k_glu occupancy 21% on a 736-block grid).
// Fix: VGPR-prefetch software pipelines. k_glu: loads for t+1 in regs before
// computing t, LDS dbuf, ds_write after compute, 1 barrier/t, GT_=8 (1440
// blocks). k_conv: linearized (t,kb) pipeline (load next step between
// ds_write and compute), epilogue = direct packed 8B stores (same-block rows
// -> L2 write-combines; no y-tile LDS round trip).

#define B_  16
#define T_  354
#define N_  64
#define H_  128
#define NS_ 32
#define BN_ (B_*N_)          // 1024 sequences
#define TP_ 384              // padded tau range for xbf rows
#define KW_ 512              // padded Krev row length
#define PAD_ 136             // LDS row stride (bf16 elems)
#define GC_ 4                // t's per k_conv block
#define NGC_ ((T_ + GC_ - 1) / GC_)   // 89
#define GT_ 8                // t's per k_glu block
#define NGT_ ((T_ + GT_ - 1) / GT_)   // 45
#define WB_ ((2 * H_ * H_) / 512)     // 64 Wbf-cast blocks

typedef __attribute__((ext_vector_type(8))) short bf16x8;
typedef __attribute__((ext_vector_type(4))) float f32x4;

static __device__ __forceinline__ unsigned short f32_to_bf16(float f) {
    unsigned int u = __float_as_uint(f);
    unsigned int r = 0x7FFFu + ((u >> 16) & 1u);   // RNE
    return (unsigned short)((u + r) >> 16);
}

// gelu(v) = v * sigmoid(1.595769122*v + 0.071354816*v^3)  (tanh approx, JAX)
static __device__ __forceinline__ float gelu_f(float v) {
    float v2 = v * v;
    float x  = v * fmaf(0.0713548162726f, v2, 1.5957691216057f);
    float sg = 1.0f / (1.0f + __expf(-x));
    return v * sg;
}

// ---------------------------------------------------------------------------
// K0: merged prep, role by blockIdx.x:
//  [0,128):        S4D taps for h=blockIdx (+ Krev 8 copies + koff scan)
//  [128,224):      x transpose-cast via LDS (64t x 64n tile)
//  [224,224+WB_):  W_out f32 -> bf16
// ---------------------------------------------------------------------------
__global__ __launch_bounds__(512) void k_pre(
        const float* __restrict__ log_dt,
        const float* __restrict__ A_re, const float* __restrict__ A_im,
        const float* __restrict__ C_re, const float* __restrict__ C_im,
        const float* __restrict__ b_in, const float* __restrict__ D,
        const float* __restrict__ x, const float* __restrict__ W_out,
        unsigned short* __restrict__ Krev, float* __restrict__ koff,
        unsigned short* __restrict__ xbf, unsigned short* __restrict__ Wbf) {
    const int blk = blockIdx.x;
    const int tid = threadIdx.x;

    if (blk >= H_ + 96) {                          // ---- Wbf cast ----
        int id = (blk - H_ - 96) * 512 + tid;
        if (id < 2 * H_ * H_) Wbf[id] = f32_to_bf16(W_out[id]);
        return;
    }
    if (blk >= H_) {                               // ---- x transpose ----
        __shared__ float xt[64][68];               // +4 pad
        int idx = blk - H_;
        int bt = idx / 6, tt = idx % 6;            // b-index, t-tile
        int r  = tid >> 3, fc = tid & 7;           // row, col-octet
        int t  = tt * 64 + r;
        float4 v0 = make_float4(0.f, 0.f, 0.f, 0.f), v1 = v0;
        if (t < T_) {
            const float* xp = x + ((size_t)bt * T_ + t) * N_ + fc * 8;
            v0 = *(const float4*)xp;
            v1 = *(const float4*)(xp + 4);
        }
        *(float4*)&xt[r][fc * 8]     = v0;
        *(float4*)&xt[r][fc * 8 + 4] = v1;
        __syncthreads();
        int n = tid >> 3, tc = tid & 7;
        unsigned short pk[8];
#pragma unroll
        for (int k = 0; k < 8; k++) pk[k] = f32_to_bf16(xt[tc * 8 + k][n]);
        *(uint4*)(xbf + (size_t)(bt * 64 + n) * TP_ + tt * 64 + tc * 8)
            = *(const uint4*)pk;
        return;
    }

    // ---- taps ----
    const int h = blk;
    const int l = tid;
    float val = 0.0f;
    if (l < T_) {
        float dt = expf(log_dt[h]);
        float fl = (float)l;
#pragma unroll 4
        for (int m = 0; m < NS_; m++) {
            float are = A_re[h * NS_ + m], aim = A_im[h * NS_ + m];
            float dre = are * dt, dim = aim * dt;
            float er  = expf(dre);
            float c1, s1; __sincosf(dim, &s1, &c1);
            float e_re = er * c1, e_im = er * s1;
            float m_re = e_re - 1.0f, m_im = e_im;
            float inv  = 1.0f / (are * are + aim * aim);
            float q_re = (m_re * are + m_im * aim) * inv;
            float q_im = (m_im * are - m_re * aim) * inv;
            float c_r = C_re[h * NS_ + m], c_i = C_im[h * NS_ + m];
            float cdre = c_r * q_re - c_i * q_im;
            float cdim = c_r * q_im + c_i * q_re;
            float el = expf(dre * fl);
            float cl, sl; __sincosf(dim * fl, &sl, &cl);
            val += el * (cdre * cl - cdim * sl);
        }
        val *= 2.0f;
        if (l == 0) val += D[h];
    }

    __shared__ float sc[512];
    sc[l] = (l < T_) ? val : 0.0f;
    __syncthreads();
    for (int off = 1; off < 512; off <<= 1) {
        float add = (l >= off) ? sc[l - off] : 0.0f;
        __syncthreads();
        sc[l] += add;
        __syncthreads();
    }

    if (l < T_) {
        koff[l * H_ + h] = b_in[h] * sc[l];
        unsigned short bv = f32_to_bf16(val);
#pragma unroll
        for (int r = 0; r < 8; r++)
            Krev[((size_t)r * H_ + h) * KW_ + (T_ - 1 - l) + r] = bv;
    }
}

// ---------------------------------------------------------------------------
// K1: conv + gelu -> Y[q][h].  Software-pipelined (t,kb) steps:
//   sync; ds_write(cur regs); global_load(next) -> regs; sync; MFMA(cur);
//   [last kb of t: gelu + packed 8B stores].
// Block = 256 thr / 4 waves, tile = 64 bn x 128 h x GC_ t's.
// Conv D[m=h][n=bn]: A = Krev windows (k_lds), B = xbf rows (x_lds).
// ---------------------------------------------------------------------------
__global__ __launch_bounds__(256, 3) void k_conv(
        const unsigned short* __restrict__ xbf,    // [1024][TP_]
        const unsigned short* __restrict__ Krev,   // [8][128][KW_]
        const float* __restrict__ koff,            // [354][128]
        const float* __restrict__ W_in,
        unsigned short* __restrict__ Y) {          // [q][h]
    __shared__ unsigned short x_lds[64 * PAD_];    // 17 KB
    __shared__ unsigned short k_lds[128 * PAD_];   // 34 KB

    const int tid   = threadIdx.x;
    const int w     = tid >> 6;
    const int lane  = tid & 63;
    const int q     = lane >> 4;
    const int l16   = lane & 15;
    const int bn0   = blockIdx.x * 64;
    const int tg0   = blockIdx.y * GC_;
    const int srow4 = lane >> 4;                   // sub-row in 4-row group
    const int scol  = l16 * 8;                     // elems (16 B)

    float win[2][4];
#pragma unroll
    for (int mt = 0; mt < 2; mt++)
#pragma unroll
        for (int rr = 0; rr < 4; rr++)
            win[mt][rr] = W_in[32 * w + 16 * mt + 4 * q + rr];

    uint4 xr[4], kr[8];                            // pipeline registers

    auto LOAD = [&](int t, int kb) {
        const int tau0 = kb << 7;
        const int L    = 353 - t + tau0;
        const int cp   = (-L) & 7;
        const unsigned short* kbase = Krev + (size_t)cp * H_ * KW_ + (L + cp);
#pragma unroll
        for (int i = 0; i < 4; i++) {
            int r = w * 16 + i * 4 + srow4;
            xr[i] = *(const uint4*)(xbf + (size_t)(bn0 + r) * TP_ + tau0 + scol);
        }
#pragma unroll
        for (int i = 0; i < 8; i++) {
            int hr = w * 32 + i * 4 + srow4;
            kr[i] = *(const uint4*)(kbase + (size_t)hr * KW_ + scol);
        }
    };
    auto WRITE = [&]() {
#pragma unroll
        for (int i = 0; i < 4; i++) {
            int r = w * 16 + i * 4 + srow4;
            *(uint4*)&x_lds[r * PAD_ + scol] = xr[i];
        }
#pragma unroll
        for (int i = 0; i < 8; i++) {
            int hr = w * 32 + i * 4 + srow4;
            *(uint4*)&k_lds[hr * PAD_ + scol] = kr[i];
        }
    };

    f32x4 cacc[2][4];
#pragma unroll
    for (int mt = 0; mt < 2; mt++)
#pragma unroll
        for (int nt = 0; nt < 4; nt++) cacc[mt][nt] = (f32x4){0.f, 0.f, 0.f, 0.f};

    int t = tg0, kb = 0;
    bool valid = true;
    LOAD(t, kb);
    while (valid) {
        int tn = t, kbn = kb + 1;
        if (kbn > (t >> 7)) { tn = t + 1; kbn = 0; }
        bool vn = (tn < T_) && (tn < tg0 + GC_);

        __syncthreads();                           // prior compute done
        WRITE();                                   // waits cur loads (vmcnt)
        if (vn) LOAD(tn, kbn);                     // prefetch next step
        __syncthreads();                           // LDS visible

        const int tau0 = kb << 7;
        const int kshi = min(3, (t - tau0) >> 5);
        for (int ks = 0; ks <= kshi; ks++) {
            bf16x8 af[2], bf[4];
#pragma unroll
            for (int mt = 0; mt < 2; mt++)
                af[mt] = *(const bf16x8*)&k_lds[(32 * w + 16 * mt + l16) * PAD_ + ks * 32 + q * 8];
#pragma unroll
            for (int nt = 0; nt < 4; nt++)
                bf[nt] = *(const bf16x8*)&x_lds[(16 * nt + l16) * PAD_ + ks * 32 + q * 8];
#pragma unroll
            for (int mt = 0; mt < 2; mt++)
#pragma unroll
                for (int nt = 0; nt < 4; nt++)
                    cacc[mt][nt] = __builtin_amdgcn_mfma_f32_16x16x32_bf16(
                        af[mt], bf[nt], cacc[mt][nt], 0, 0, 0);
        }

        if (kb == (t >> 7)) {                      // last kb -> epilogue for t
#pragma unroll
            for (int mt = 0; mt < 2; mt++) {
                int h0 = 32 * w + 16 * mt + 4 * q;
#pragma unroll
                for (int nt = 0; nt < 4; nt++) {
                    unsigned short pk[4];
#pragma unroll
                    for (int rr = 0; rr < 4; rr++) {
                        float v = fmaf(cacc[mt][nt][rr], win[mt][rr],
                                       koff[t * H_ + h0 + rr]);
                        pk[rr] = f32_to_bf16(gelu_f(v));
                    }
                    int bn = bn0 + 16 * nt + l16;
                    *(uint2*)(Y + ((size_t)t * BN_ + bn) * H_ + h0)
                        = *(const uint2*)pk;
                    cacc[mt][nt] = (f32x4){0.f, 0.f, 0.f, 0.f};
                }
            }
        }
        t = tn; kb = kbn; valid = vn;
    }
}

// ---------------------------------------------------------------------------
// K2: GLU GEMM + t-pool.  D[m=j][n=bn], A = W frags (VGPR-persistent),
// B = Y-tile, double-buffered LDS + VGPR prefetch: loads for t+1 issued
// before computing t; ds_write after compute; ONE barrier per t.
// Flush: 16 consecutive j per 64B line (coalesced atomic write-through).
// ---------------------------------------------------------------------------
__global__ __launch_bounds__(256, 4) void k_glu(
        const unsigned short* __restrict__ Y,      // [q][h]
        const unsigned short* __restrict__ Wbf,    // [256][128]
        const float* __restrict__ b_out,
        float* __restrict__ node_sum) {
    __shared__ unsigned short Yt[2][64 * PAD_];    // 2 x 17 KB

    const int tid   = threadIdx.x;
    const int w     = tid >> 6;
    const int lane  = tid & 63;
    const int q     = lane >> 4;
    const int l16   = lane & 15;
    const int jg    = blockIdx.x & 1;
    const int bn0   = (blockIdx.x >> 1) * 64;
    const int tg0   = blockIdx.y * GT_;
    const int jlow  = jg * 64 + w * 16;
    const int jhigh = jlow + 128;
    const int srow4 = lane >> 4;
    const int scol  = l16 * 8;

    bf16x8 wfrag[2][4];                            // [low/high][ks]
#pragma unroll
    for (int ks = 0; ks < 4; ks++) {
        wfrag[0][ks] = *(const bf16x8*)(Wbf + (size_t)(jlow  + l16) * H_ + ks * 32 + q * 8);
        wfrag[1][ks] = *(const bf16x8*)(Wbf + (size_t)(jhigh + l16) * H_ + ks * 32 + q * 8);
    }
    float bo1[4], bo2[4];
#pragma unroll
    for (int rr = 0; rr < 4; rr++) {
        bo1[rr] = b_out[jlow  + 4 * q + rr];
        bo2[rr] = b_out[jhigh + 4 * q + rr];
    }

    uint4 pre[4];
    auto LOADT = [&](int t) {
#pragma unroll
        for (int i = 0; i < 4; i++) {
            int r = w * 16 + i * 4 + srow4;
            pre[i] = *(const uint4*)(Y + ((size_t)t * BN_ + bn0 + r) * H_ + scol);
        }
    };
    auto WRITEB = [&](int b) {
#pragma unroll
        for (int i = 0; i < 4; i++) {
            int r = w * 16 + i * 4 + srow4;
            *(uint4*)&Yt[b][r * PAD_ + scol] = pre[i];
        }
    };

    f32x4 zacc[4];
#pragma unroll
    for (int nt = 0; nt < 4; nt++) zacc[nt] = (f32x4){0.f, 0.f, 0.f, 0.f};

    LOADT(tg0);
    WRITEB(0);
    __syncthreads();

    for (int g = 0; g < GT_; g++) {
        const int t = tg0 + g;
        if (t >= T_) break;                        // block-uniform
        const bool hn = (g + 1 < GT_) && (t + 1 < T_);
        if (hn) LOADT(t + 1);                      // prefetch next t

        f32x4 gacc[2][4];
#pragma unroll
        for (int mt = 0; mt < 2; mt++)
#pragma unroll
            for (int nt = 0; nt < 4; nt++) gacc[mt][nt] = (f32x4){0.f, 0.f, 0.f, 0.f};

        const unsigned short* buf = Yt[g & 1];
#pragma unroll
        for (int ks = 0; ks < 4; ks++) {
            bf16x8 yf[4];
#pragma unroll
            for (int nt = 0; nt < 4; nt++)
                yf[nt] = *(const bf16x8*)&buf[(16 * nt + l16) * PAD_ + ks * 32 + q * 8];
#pragma unroll
            for (int mt = 0; mt < 2; mt++)
#pragma unroll
                for (int nt = 0; nt < 4; nt++)
                    gacc[mt][nt] = __builtin_amdgcn_mfma_f32_16x16x32_bf16(
                        wfrag[mt][ks], yf[nt], gacc[mt][nt], 0, 0, 0);
        }

#pragma unroll
        for (int nt = 0; nt < 4; nt++)
#pragma unroll
            for (int rr = 0; rr < 4; rr++) {
                float a  = gacc[0][nt][rr] + bo1[rr];
                float bs = gacc[1][nt][rr] + bo2[rr];
                float sg = 1.0f / (1.0f + __expf(-bs));
                zacc[nt][rr] += a * sg;
            }

        if (hn) WRITEB((g + 1) & 1);               // loads long done by now
        __syncthreads();                           // one barrier per t
    }

    // flush: lanes sharing a 64B line (16 consecutive j at fixed bn)
#pragma unroll
    for (int nt = 0; nt < 4; nt++)
#pragma unroll
        for (int rr = 0; rr < 4; rr++) {
            int bn = bn0 + 16 * nt + l16;
            int j  = jlow + 4 * q + rr;
            atomicAdd(&node_sum[bn * H_ + j], zacc[nt][rr]);
        }
}

// ---------------------------------------------------------------------------
// K3: logits[b] = (1/(T*N)) * sum_{n,h} node_sum[b*64+n][h] * W_cls[h] + b_cls
// ---------------------------------------------------------------------------
__global__ void k_cls(const float* __restrict__ node_sum,
                      const float* __restrict__ W_cls, const float* __restrict__ b_cls,
                      float* __restrict__ out) {
    const int b = blockIdx.x, tid = threadIdx.x;
    float s = 0.0f;
    for (int i = tid; i < N_ * H_; i += 256)
        s += node_sum[b * (N_ * H_) + i] * W_cls[i & (H_ - 1)];
    __shared__ float red[256];
    red[tid] = s;
    __syncthreads();
    for (int off = 128; off > 0; off >>= 1) {
        if (tid < off) red[tid] += red[tid + off];
        __syncthreads();
    }
    if (tid == 0) out[b] = red[0] * (1.0f / (354.0f * 64.0f)) + b_cls[0];
}

// ---------------------------------------------------------------------------
extern "C" void kernel_launch(void* const* d_in, const int* in_sizes, int n_in,
                              void* d_out, int out_size, void* d_ws, size_t ws_size,
                              hipStream_t stream) {
    const float* x      = (const float*)d_in[0];
    const float* W_in   = (const float*)d_in[1];
    const float* b_in   = (const float*)d_in[2];
    const float* log_dt = (const float*)d_in[3];
    const float* A_re   = (const float*)d_in[4];
    const float* A_im   = (const float*)d_in[5];
    const float* C_re   = (const float*)d_in[6];
    const float* C_im   = (const float*)d_in[7];
    const float* D      = (const float*)d_in[8];
    const float* W_out  = (const float*)d_in[9];
    const float* b_out  = (const float*)d_in[10];
    const float* W_cls  = (const float*)d_in[11];
    const float* b_cls  = (const float*)d_in[12];

    char* ws = (char*)d_ws;
    // [node_sum 512K][Krev 1M] contiguous -> ONE memset; rest fully written
    float*          node_sum = (float*)(ws + 0);                  //   524288 B
    unsigned short* Krev     = (unsigned short*)(ws + 524288);    //  1048576 B
    float*          koff     = (float*)(ws + 1572864);            //   181248 B
    unsigned short* xbf      = (unsigned short*)(ws + 1754112);   //   786432 B
    unsigned short* Wbf      = (unsigned short*)(ws + 2540544);   //    65536 B
    unsigned short* Y        = (unsigned short*)(ws + 2606080);   // 92798976 B

    hipMemsetAsync(ws, 0, 1572864, stream);
    k_pre<<<dim3(H_ + 96 + WB_), dim3(512), 0, stream>>>(
        log_dt, A_re, A_im, C_re, C_im, b_in, D, x, W_out, Krev, koff, xbf, Wbf);
    k_conv<<<dim3(BN_ / 64, NGC_), dim3(256), 0, stream>>>(
        xbf, Krev, koff, W_in, Y);
    k_glu<<<dim3(2 * BN_ / 64, NGT_), dim3(256), 0, stream>>>(
        Y, Wbf, b_out, node_sum);
    k_cls<<<dim3(B_), dim3(256), 0, stream>>>(node_sum, W_cls, b_cls, (float*)d_out);
}

// Round 12
// 281.341 us; speedup vs baseline: 1.4450x; 1.4450x over previous
//
#include <hip/hip_runtime.h>
#include <hip/hip_bf16.h>

// R12: R11's VGPR-prefetch pipelines spilled to scratch (regs live across
// barriers in a while-loop; WRITE 95->539MB, FETCH->127MB, VGPR_Count 72).
// Revert to R10 base + two spill-proof changes:
//  - k_conv: t-pair blocks, kb-outer; x-tile staged ONCE per kb (17KB LDS,
//    global_load_lds); K a-frags loaded DIRECT from L2-hot Krev into
//    short-lived regs (no k_lds, fewer barriers). Full 4-ks loops (tail taps
//    are exact zeros) keep all frag arrays statically indexed -> registers.
//  - k_glu: R10 structure, GT_ 16->8 (1440 blocks, ~5.6/CU) for TLP.

#define B_  16
#define T_  354
#define N_  64
#define H_  128
#define NS_ 32
#define BN_ (B_*N_)          // 1024 sequences
#define TP_ 384              // padded tau range for xbf rows
#define KW_ 512              // padded Krev row length
#define PAD_ 136             // LDS row stride (bf16 elems)
#define GT_ 8                // t's per k_glu block
#define NGT_ ((T_ + GT_ - 1) / GT_)   // 45
#define WB_ ((2 * H_ * H_) / 512)     // 64 Wbf-cast blocks

typedef __attribute__((ext_vector_type(8))) short bf16x8;
typedef __attribute__((ext_vector_type(4))) float f32x4;

static __device__ __forceinline__ unsigned short f32_to_bf16(float f) {
    unsigned int u = __float_as_uint(f);
    unsigned int r = 0x7FFFu + ((u >> 16) & 1u);   // RNE
    return (unsigned short)((u + r) >> 16);
}

// async global->LDS, 4 B per lane: one 256 B row per instruction.
static __device__ __forceinline__ void gload_lds4(const void* g, void* l) {
    __builtin_amdgcn_global_load_lds(
        (const __attribute__((address_space(1))) unsigned int*)g,
        (__attribute__((address_space(3))) unsigned int*)l, 4, 0, 0);
}

// gelu(v) = v * sigmoid(1.595769122*v + 0.071354816*v^3)  (tanh approx, JAX)
static __device__ __forceinline__ float gelu_f(float v) {
    float v2 = v * v;
    float x  = v * fmaf(0.0713548162726f, v2, 1.5957691216057f);
    float sg = 1.0f / (1.0f + __expf(-x));
    return v * sg;
}

// ---------------------------------------------------------------------------
// K0: merged prep, role by blockIdx.x:
//  [0,128):        S4D taps for h=blockIdx (+ Krev 8 copies + koff scan)
//  [128,224):      x transpose-cast via LDS (64t x 64n tile)
//  [224,224+WB_):  W_out f32 -> bf16
// ---------------------------------------------------------------------------
__global__ __launch_bounds__(512) void k_pre(
        const float* __restrict__ log_dt,
        const float* __restrict__ A_re, const float* __restrict__ A_im,
        const float* __restrict__ C_re, const float* __restrict__ C_im,
        const float* __restrict__ b_in, const float* __restrict__ D,
        const float* __restrict__ x, const float* __restrict__ W_out,
        unsigned short* __restrict__ Krev, float* __restrict__ koff,
        unsigned short* __restrict__ xbf, unsigned short* __restrict__ Wbf) {
    const int blk = blockIdx.x;
    const int tid = threadIdx.x;

    if (blk >= H_ + 96) {                          // ---- Wbf cast ----
        int id = (blk - H_ - 96) * 512 + tid;
        if (id < 2 * H_ * H_) Wbf[id] = f32_to_bf16(W_out[id]);
        return;
    }
    if (blk >= H_) {                               // ---- x transpose ----
        __shared__ float xt[64][68];               // +4 pad
        int idx = blk - H_;
        int bt = idx / 6, tt = idx % 6;            // b-index, t-tile
        int r  = tid >> 3, fc = tid & 7;           // row, col-octet
        int t  = tt * 64 + r;
        float4 v0 = make_float4(0.f, 0.f, 0.f, 0.f), v1 = v0;
        if (t < T_) {
            const float* xp = x + ((size_t)bt * T_ + t) * N_ + fc * 8;
            v0 = *(const float4*)xp;
            v1 = *(const float4*)(xp + 4);
        }
        *(float4*)&xt[r][fc * 8]     = v0;
        *(float4*)&xt[r][fc * 8 + 4] = v1;
        __syncthreads();
        int n = tid >> 3, tc = tid & 7;
        unsigned short pk[8];
#pragma unroll
        for (int k = 0; k < 8; k++) pk[k] = f32_to_bf16(xt[tc * 8 + k][n]);
        *(uint4*)(xbf + (size_t)(bt * 64 + n) * TP_ + tt * 64 + tc * 8)
            = *(const uint4*)pk;
        return;
    }

    // ---- taps ----
    const int h = blk;
    const int l = tid;
    float val = 0.0f;
    if (l < T_) {
        float dt = expf(log_dt[h]);
        float fl = (float)l;
#pragma unroll 4
        for (int m = 0; m < NS_; m++) {
            float are = A_re[h * NS_ + m], aim = A_im[h * NS_ + m];
            float dre = are * dt, dim = aim * dt;
            float er  = expf(dre);
            float c1, s1; __sincosf(dim, &s1, &c1);
            float e_re = er * c1, e_im = er * s1;
            float m_re = e_re - 1.0f, m_im = e_im;
            float inv  = 1.0f / (are * are + aim * aim);
            float q_re = (m_re * are + m_im * aim) * inv;
            float q_im = (m_im * are - m_re * aim) * inv;
            float c_r = C_re[h * NS_ + m], c_i = C_im[h * NS_ + m];
            float cdre = c_r * q_re - c_i * q_im;
            float cdim = c_r * q_im + c_i * q_re;
            float el = expf(dre * fl);
            float cl, sl; __sincosf(dim * fl, &sl, &cl);
            val += el * (cdre * cl - cdim * sl);
        }
        val *= 2.0f;
        if (l == 0) val += D[h];
    }

    __shared__ float sc[512];
    sc[l] = (l < T_) ? val : 0.0f;
    __syncthreads();
    for (int off = 1; off < 512; off <<= 1) {
        float add = (l >= off) ? sc[l - off] : 0.0f;
        __syncthreads();
        sc[l] += add;
        __syncthreads();
    }

    if (l < T_) {
        koff[l * H_ + h] = b_in[h] * sc[l];
        unsigned short bv = f32_to_bf16(val);
#pragma unroll
        for (int r = 0; r < 8; r++)
            Krev[((size_t)r * H_ + h) * KW_ + (T_ - 1 - l) + r] = bv;
    }
}

// ---------------------------------------------------------------------------
// K1: conv + gelu -> Y[q][h].  Block = 64 bn x 128 h x t-PAIR (t0, t0+1).
// kb-outer: x-tile (t-independent) staged once per kb via global_load_lds;
// K a-frags loaded direct from L2-hot Krev (8 x 16B aligned loads per t,kb;
// copy-select cp=(-L)&7).  Full 4-ks loops: taps beyond t and x beyond T are
// exact zeros (memset / zero-pad), so no runtime-bounded arrays -> no spills.
// Epilogue per t: gelu -> y-tile in x_lds -> coalesced 256B-row stores.
// ---------------------------------------------------------------------------
__global__ __launch_bounds__(256, 3) void k_conv(
        const unsigned short* __restrict__ xbf,    // [1024][TP_]
        const unsigned short* __restrict__ Krev,   // [8][128][KW_]
        const float* __restrict__ koff,            // [354][128]
        const float* __restrict__ W_in,
        unsigned short* __restrict__ Y) {          // [q][h]
    __shared__ unsigned short x_lds[64 * PAD_];    // 17 KB

    const int tid  = threadIdx.x;
    const int w    = tid >> 6;
    const int lane = tid & 63;
    const int q    = lane >> 4;
    const int l16  = lane & 15;
    const int bn0  = blockIdx.x * 64;
    const int t0   = blockIdx.y * 2;               // t-pair
    const int nkb  = ((t0 + 1) >> 7) + 1;

    float win[2][4];
#pragma unroll
    for (int mt = 0; mt < 2; mt++)
#pragma unroll
        for (int rr = 0; rr < 4; rr++)
            win[mt][rr] = W_in[32 * w + 16 * mt + 4 * q + rr];

    f32x4 cacc[2][2][4];                           // [tt][mt][nt]
#pragma unroll
    for (int tt = 0; tt < 2; tt++)
#pragma unroll
        for (int mt = 0; mt < 2; mt++)
#pragma unroll
            for (int nt = 0; nt < 4; nt++)
                cacc[tt][mt][nt] = (f32x4){0.f, 0.f, 0.f, 0.f};

    for (int kb = 0; kb < nkb; kb++) {
        const int tau0 = kb << 7;
        __syncthreads();                           // prior ds_reads done
        // stage x-tile once per kb (shared by both t): wave w rows [16w,16w+16)
#pragma unroll
        for (int i = 0; i < 16; i++) {
            int r = w * 16 + i;
            gload_lds4(xbf + (size_t)(bn0 + r) * TP_ + tau0 + lane * 2,
                       &x_lds[r * PAD_]);
        }
        __syncthreads();                           // LDS visible

#pragma unroll
        for (int tt = 0; tt < 2; tt++) {
            const int t = t0 + tt;
            if (tau0 > t) continue;                // only t0 at a kb boundary
            const int L  = 353 - t + tau0;         // in [226,353]
            const int cp = (-L) & 7;               // 16B-aligned copy
            const unsigned short* kbase = Krev + (size_t)cp * H_ * KW_ + (L + cp);

            // preload all 8 K a-frags (short-lived, statically indexed)
            bf16x8 kf[4][2];
#pragma unroll
            for (int ks = 0; ks < 4; ks++)
#pragma unroll
                for (int mt = 0; mt < 2; mt++)
                    kf[ks][mt] = *(const bf16x8*)(kbase
                        + (size_t)(32 * w + 16 * mt + l16) * KW_ + ks * 32 + q * 8);

#pragma unroll
            for (int ks = 0; ks < 4; ks++) {
                bf16x8 bf[4];
#pragma unroll
                for (int nt = 0; nt < 4; nt++)
                    bf[nt] = *(const bf16x8*)&x_lds[(16 * nt + l16) * PAD_ + ks * 32 + q * 8];
#pragma unroll
                for (int mt = 0; mt < 2; mt++)
#pragma unroll
                    for (int nt = 0; nt < 4; nt++)
                        cacc[tt][mt][nt] = __builtin_amdgcn_mfma_f32_16x16x32_bf16(
                            kf[ks][mt], bf[nt], cacc[tt][mt][nt], 0, 0, 0);
            }
        }
    }

    // ---- epilogue per t: gelu -> y-tile [bn][h] in x_lds -> coalesced store
#pragma unroll
    for (int tt = 0; tt < 2; tt++) {
        const int t = t0 + tt;
        __syncthreads();                           // x_lds free of readers
#pragma unroll
        for (int mt = 0; mt < 2; mt++) {
            int h0 = 32 * w + 16 * mt + 4 * q;
#pragma unroll
            for (int nt = 0; nt < 4; nt++) {
                unsigned short pk[4];
#pragma unroll
                for (int rr = 0; rr < 4; rr++) {
                    float v = fmaf(cacc[tt][mt][nt][rr], win[mt][rr],
                                   koff[t * H_ + h0 + rr]);
                    pk[rr] = f32_to_bf16(gelu_f(v));
                }
                *(uint2*)&x_lds[(16 * nt + l16) * PAD_ + h0] = *(const uint2*)pk;
            }
        }
        __syncthreads();
#pragma unroll
        for (int i = 0; i < 4; i++) {
            int c    = i * 256 + tid;
            int row  = c >> 4;
            int col8 = (c & 15) * 8;
            uint4 v = *(const uint4*)&x_lds[row * PAD_ + col8];
            *(uint4*)(Y + ((size_t)t * BN_ + bn0 + row) * H_ + col8) = v;
        }
    }
}

// ---------------------------------------------------------------------------
// K2: GLU GEMM + t-pool (R10 structure).  D[m=j][n=bn], A = W frags
// (VGPR-persistent, 16 j-pairs per wave), B = Y-tile staged per t via
// global_load_lds.  GT_=8 -> 1440 blocks for TLP.  Flush: 16 consecutive j
// per 64B line (coalesced atomic write-through).
// ---------------------------------------------------------------------------
__global__ __launch_bounds__(256, 4) void k_glu(
        const unsigned short* __restrict__ Y,      // [q][h]
        const unsigned short* __restrict__ Wbf,    // [256][128]
        const float* __restrict__ b_out,
        float* __restrict__ node_sum) {
    __shared__ unsigned short Yt[64 * PAD_];       // 17 KB

    const int tid  = threadIdx.x;
    const int w    = tid >> 6;
    const int lane = tid & 63;
    const int q    = lane >> 4;
    const int l16  = lane & 15;
    const int jg   = blockIdx.x & 1;
    const int bn0  = (blockIdx.x >> 1) * 64;
    const int tg0  = blockIdx.y * GT_;
    const int jlow = jg * 64 + w * 16;
    const int jhigh = jlow + 128;

    bf16x8 wfrag[2][4];                            // [low/high][ks]
#pragma unroll
    for (int ks = 0; ks < 4; ks++) {
        wfrag[0][ks] = *(const bf16x8*)(Wbf + (size_t)(jlow  + l16) * H_ + ks * 32 + q * 8);
        wfrag[1][ks] = *(const bf16x8*)(Wbf + (size_t)(jhigh + l16) * H_ + ks * 32 + q * 8);
    }
    float bo1[4], bo2[4];
#pragma unroll
    for (int rr = 0; rr < 4; rr++) {
        bo1[rr] = b_out[jlow  + 4 * q + rr];
        bo2[rr] = b_out[jhigh + 4 * q + rr];
    }

    f32x4 zacc[4];
#pragma unroll
    for (int nt = 0; nt < 4; nt++) zacc[nt] = (f32x4){0.f, 0.f, 0.f, 0.f};

    for (int g = 0; g < GT_; g++) {
        const int t = tg0 + g;
        if (t >= T_) break;                        // block-uniform
        __syncthreads();
#pragma unroll
        for (int i = 0; i < 16; i++) {
            int r = w * 16 + i;
            gload_lds4(Y + ((size_t)t * BN_ + bn0 + r) * H_ + lane * 2,
                       &Yt[r * PAD_]);
        }
        __syncthreads();

        f32x4 gacc[2][4];
#pragma unroll
        for (int mt = 0; mt < 2; mt++)
#pragma unroll
            for (int nt = 0; nt < 4; nt++) gacc[mt][nt] = (f32x4){0.f, 0.f, 0.f, 0.f};

#pragma unroll
        for (int ks = 0; ks < 4; ks++) {
            bf16x8 yf[4];
#pragma unroll
            for (int nt = 0; nt < 4; nt++)
                yf[nt] = *(const bf16x8*)&Yt[(16 * nt + l16) * PAD_ + ks * 32 + q * 8];
#pragma unroll
            for (int mt = 0; mt < 2; mt++)
#pragma unroll
                for (int nt = 0; nt < 4; nt++)
                    gacc[mt][nt] = __builtin_amdgcn_mfma_f32_16x16x32_bf16(
                        wfrag[mt][ks], yf[nt], gacc[mt][nt], 0, 0, 0);
        }

#pragma unroll
        for (int nt = 0; nt < 4; nt++)
#pragma unroll
            for (int rr = 0; rr < 4; rr++) {
                float a  = gacc[0][nt][rr] + bo1[rr];
                float bs = gacc[1][nt][rr] + bo2[rr];
                float sg = 1.0f / (1.0f + __expf(-bs));
                zacc[nt][rr] += a * sg;
            }
    }

    // flush: lanes sharing a 64B line (16 consecutive j at fixed bn)
#pragma unroll
    for (int nt = 0; nt < 4; nt++)
#pragma unroll
        for (int rr = 0; rr < 4; rr++) {
            int bn = bn0 + 16 * nt + l16;
            int j  = jlow + 4 * q + rr;
            atomicAdd(&node_sum[bn * H_ + j], zacc[nt][rr]);
        }
}

// ---------------------------------------------------------------------------
// K3: logits[b] = (1/(T*N)) * sum_{n,h} node_sum[b*64+n][h] * W_cls[h] + b_cls
// ---------------------------------------------------------------------------
__global__ void k_cls(const float* __restrict__ node_sum,
                      const float* __restrict__ W_cls, const float* __restrict__ b_cls,
                      float* __restrict__ out) {
    const int b = blockIdx.x, tid = threadIdx.x;
    float s = 0.0f;
    for (int i = tid; i < N_ * H_; i += 256)
        s += node_sum[b * (N_ * H_) + i] * W_cls[i & (H_ - 1)];
    __shared__ float red[256];
    red[tid] = s;
    __syncthreads();
    for (int off = 128; off > 0; off >>= 1) {
        if (tid < off) red[tid] += red[tid + off];
        __syncthreads();
    }
    if (tid == 0) out[b] = red[0] * (1.0f / (354.0f * 64.0f)) + b_cls[0];
}

// ---------------------------------------------------------------------------
extern "C" void kernel_launch(void* const* d_in, const int* in_sizes, int n_in,
                              void* d_out, int out_size, void* d_ws, size_t ws_size,
                              hipStream_t stream) {
    const float* x      = (const float*)d_in[0];
    const float* W_in   = (const float*)d_in[1];
    const float* b_in   = (const float*)d_in[2];
    const float* log_dt = (const float*)d_in[3];
    const float* A_re   = (const float*)d_in[4];
    const float* A_im   = (const float*)d_in[5];
    const float* C_re   = (const float*)d_in[6];
    const float* C_im   = (const float*)d_in[7];
    const float* D      = (const float*)d_in[8];
    const float* W_out  = (const float*)d_in[9];
    const float* b_out  = (const float*)d_in[10];
    const float* W_cls  = (const float*)d_in[11];
    const float* b_cls  = (const float*)d_in[12];

    char* ws = (char*)d_ws;
    // [node_sum 512K][Krev 1M] contiguous -> ONE memset; rest fully written
    float*          node_sum = (float*)(ws + 0);                  //   524288 B
    unsigned short* Krev     = (unsigned short*)(ws + 524288);    //  1048576 B
    float*          koff     = (float*)(ws + 1572864);            //   181248 B
    unsigned short* xbf      = (unsigned short*)(ws + 1754112);   //   786432 B
    unsigned short* Wbf      = (unsigned short*)(ws + 2540544);   //    65536 B
    unsigned short* Y        = (unsigned short*)(ws + 2606080);   // 92798976 B

    hipMemsetAsync(ws, 0, 1572864, stream);
    k_pre<<<dim3(H_ + 96 + WB_), dim3(512), 0, stream>>>(
        log_dt, A_re, A_im, C_re, C_im, b_in, D, x, W_out, Krev, koff, xbf, Wbf);
    k_conv<<<dim3(BN_ / 64, T_ / 2), dim3(256), 0, stream>>>(
        xbf, Krev, koff, W_in, Y);
    k_glu<<<dim3(2 * BN_ / 64, NGT_), dim3(256), 0, stream>>>(
        Y, Wbf, b_out, node_sum);
    k_cls<<<dim3(B_), dim3(256), 0, stream>>>(node_sum, W_cls, b_cls, (float*)d_out);
}

// Round 13
// 257.432 us; speedup vs baseline: 1.5792x; 1.0929x over previous
//
#include <hip/hip_runtime.h>
#include <hip/hip_bf16.h>

// R13: R12 lessons — GT_=8 doubled atomic write-through (48->94MB) and
// regressed k_glu 89->114us; revert GT_=16. Both GEMMs still latency-bound on
// the stage->drain->compute serial shape. Fix with the spill-proof pipeline:
// double-buffered LDS fed by global_load_lds (no VGPR transit), stage(next)
// issued after the barrier and before compute(cur) so the next barrier's
// vmcnt(0) drain finds the loads already complete. k_glu: 2x17KB dbuf over t.
// k_conv: R12 slim structure (K direct from L2) + 2x17KB dbuf over kb, 3/CU.

#define B_  16
#define T_  354
#define N_  64
#define H_  128
#define NS_ 32
#define BN_ (B_*N_)          // 1024 sequences
#define TP_ 384              // padded tau range for xbf rows
#define KW_ 512              // padded Krev row length
#define PAD_ 136             // LDS row stride (bf16 elems)
#define GT_ 16               // t's per k_glu block
#define NGT_ ((T_ + GT_ - 1) / GT_)   // 23
#define WB_ ((2 * H_ * H_) / 512)     // 64 Wbf-cast blocks

typedef __attribute__((ext_vector_type(8))) short bf16x8;
typedef __attribute__((ext_vector_type(4))) float f32x4;

static __device__ __forceinline__ unsigned short f32_to_bf16(float f) {
    unsigned int u = __float_as_uint(f);
    unsigned int r = 0x7FFFu + ((u >> 16) & 1u);   // RNE
    return (unsigned short)((u + r) >> 16);
}

// async global->LDS, 4 B per lane: one 256 B row per instruction.
static __device__ __forceinline__ void gload_lds4(const void* g, void* l) {
    __builtin_amdgcn_global_load_lds(
        (const __attribute__((address_space(1))) unsigned int*)g,
        (__attribute__((address_space(3))) unsigned int*)l, 4, 0, 0);
}

// gelu(v) = v * sigmoid(1.595769122*v + 0.071354816*v^3)  (tanh approx, JAX)
static __device__ __forceinline__ float gelu_f(float v) {
    float v2 = v * v;
    float x  = v * fmaf(0.0713548162726f, v2, 1.5957691216057f);
    float sg = 1.0f / (1.0f + __expf(-x));
    return v * sg;
}

// ---------------------------------------------------------------------------
// K0: merged prep, role by blockIdx.x:
//  [0,128):        S4D taps for h=blockIdx (+ Krev 8 copies + koff scan)
//  [128,224):      x transpose-cast via LDS (64t x 64n tile)
//  [224,224+WB_):  W_out f32 -> bf16
// ---------------------------------------------------------------------------
__global__ __launch_bounds__(512) void k_pre(
        const float* __restrict__ log_dt,
        const float* __restrict__ A_re, const float* __restrict__ A_im,
        const float* __restrict__ C_re, const float* __restrict__ C_im,
        const float* __restrict__ b_in, const float* __restrict__ D,
        const float* __restrict__ x, const float* __restrict__ W_out,
        unsigned short* __restrict__ Krev, float* __restrict__ koff,
        unsigned short* __restrict__ xbf, unsigned short* __restrict__ Wbf) {
    const int blk = blockIdx.x;
    const int tid = threadIdx.x;

    if (blk >= H_ + 96) {                          // ---- Wbf cast ----
        int id = (blk - H_ - 96) * 512 + tid;
        if (id < 2 * H_ * H_) Wbf[id] = f32_to_bf16(W_out[id]);
        return;
    }
    if (blk >= H_) {                               // ---- x transpose ----
        __shared__ float xt[64][68];               // +4 pad
        int idx = blk - H_;
        int bt = idx / 6, tt = idx % 6;            // b-index, t-tile
        int r  = tid >> 3, fc = tid & 7;           // row, col-octet
        int t  = tt * 64 + r;
        float4 v0 = make_float4(0.f, 0.f, 0.f, 0.f), v1 = v0;
        if (t < T_) {
            const float* xp = x + ((size_t)bt * T_ + t) * N_ + fc * 8;
            v0 = *(const float4*)xp;
            v1 = *(const float4*)(xp + 4);
        }
        *(float4*)&xt[r][fc * 8]     = v0;
        *(float4*)&xt[r][fc * 8 + 4] = v1;
        __syncthreads();
        int n = tid >> 3, tc = tid & 7;
        unsigned short pk[8];
#pragma unroll
        for (int k = 0; k < 8; k++) pk[k] = f32_to_bf16(xt[tc * 8 + k][n]);
        *(uint4*)(xbf + (size_t)(bt * 64 + n) * TP_ + tt * 64 + tc * 8)
            = *(const uint4*)pk;
        return;
    }

    // ---- taps ----
    const int h = blk;
    const int l = tid;
    float val = 0.0f;
    if (l < T_) {
        float dt = expf(log_dt[h]);
        float fl = (float)l;
#pragma unroll 4
        for (int m = 0; m < NS_; m++) {
            float are = A_re[h * NS_ + m], aim = A_im[h * NS_ + m];
            float dre = are * dt, dim = aim * dt;
            float er  = expf(dre);
            float c1, s1; __sincosf(dim, &s1, &c1);
            float e_re = er * c1, e_im = er * s1;
            float m_re = e_re - 1.0f, m_im = e_im;
            float inv  = 1.0f / (are * are + aim * aim);
            float q_re = (m_re * are + m_im * aim) * inv;
            float q_im = (m_im * are - m_re * aim) * inv;
            float c_r = C_re[h * NS_ + m], c_i = C_im[h * NS_ + m];
            float cdre = c_r * q_re - c_i * q_im;
            float cdim = c_r * q_im + c_i * q_re;
            float el = expf(dre * fl);
            float cl, sl; __sincosf(dim * fl, &sl, &cl);
            val += el * (cdre * cl - cdim * sl);
        }
        val *= 2.0f;
        if (l == 0) val += D[h];
    }

    __shared__ float sc[512];
    sc[l] = (l < T_) ? val : 0.0f;
    __syncthreads();
    for (int off = 1; off < 512; off <<= 1) {
        float add = (l >= off) ? sc[l - off] : 0.0f;
        __syncthreads();
        sc[l] += add;
        __syncthreads();
    }

    if (l < T_) {
        koff[l * H_ + h] = b_in[h] * sc[l];
        unsigned short bv = f32_to_bf16(val);
#pragma unroll
        for (int r = 0; r < 8; r++)
            Krev[((size_t)r * H_ + h) * KW_ + (T_ - 1 - l) + r] = bv;
    }
}

// ---------------------------------------------------------------------------
// K1: conv + gelu -> Y[q][h].  Block = 64 bn x 128 h x t-PAIR (t0, t0+1).
// kb-outer with LDS double-buffer: x-tile(kb+1) staged (global_load_lds, no
// VGPR transit) right after the barrier, before compute(kb).  K a-frags
// loaded direct from L2-hot Krev (copy-select cp=(-L)&7, 16B aligned) into
// short-lived statically-indexed regs.  Full 4-ks loops (tail taps / x pad
// are exact zeros).  Epilogue per t: gelu -> y-tile in buf0 -> coalesced
// 256B-row stores.
// ---------------------------------------------------------------------------
__global__ __launch_bounds__(256, 3) void k_conv(
        const unsigned short* __restrict__ xbf,    // [1024][TP_]
        const unsigned short* __restrict__ Krev,   // [8][128][KW_]
        const float* __restrict__ koff,            // [354][128]
        const float* __restrict__ W_in,
        unsigned short* __restrict__ Y) {          // [q][h]
    __shared__ unsigned short x_lds[2][64 * PAD_]; // 2 x 17 KB

    const int tid  = threadIdx.x;
    const int w    = tid >> 6;
    const int lane = tid & 63;
    const int q    = lane >> 4;
    const int l16  = lane & 15;
    const int bn0  = blockIdx.x * 64;
    const int t0   = blockIdx.y * 2;               // t-pair
    const int nkb  = (t0 >> 7) + 1;

    float win[2][4];
#pragma unroll
    for (int mt = 0; mt < 2; mt++)
#pragma unroll
        for (int rr = 0; rr < 4; rr++)
            win[mt][rr] = W_in[32 * w + 16 * mt + 4 * q + rr];

    f32x4 cacc[2][2][4];                           // [tt][mt][nt]
#pragma unroll
    for (int tt = 0; tt < 2; tt++)
#pragma unroll
        for (int mt = 0; mt < 2; mt++)
#pragma unroll
            for (int nt = 0; nt < 4; nt++)
                cacc[tt][mt][nt] = (f32x4){0.f, 0.f, 0.f, 0.f};

    // prologue: stage kb=0 into buf0
#pragma unroll
    for (int i = 0; i < 16; i++) {
        int r = w * 16 + i;
        gload_lds4(xbf + (size_t)(bn0 + r) * TP_ + lane * 2,
                   &x_lds[0][r * PAD_]);
    }

    for (int kb = 0; kb < nkb; kb++) {
        const int tau0 = kb << 7;
        __syncthreads();                           // drain stage(kb); buf safe
        if (kb + 1 < nkb) {                        // prefetch kb+1 (no wait)
            const int taun = (kb + 1) << 7;
#pragma unroll
            for (int i = 0; i < 16; i++) {
                int r = w * 16 + i;
                gload_lds4(xbf + (size_t)(bn0 + r) * TP_ + taun + lane * 2,
                           &x_lds[(kb + 1) & 1][r * PAD_]);
            }
        }
        const unsigned short* xb = x_lds[kb & 1];

#pragma unroll
        for (int tt = 0; tt < 2; tt++) {
            const int t  = t0 + tt;
            const int L  = 353 - t + tau0;         // >= 0 (tau0 <= t0 <= t)
            const int cp = (-L) & 7;               // 16B-aligned copy
            const unsigned short* kbase = Krev + (size_t)cp * H_ * KW_ + (L + cp);

            bf16x8 kf[4][2];                       // short-lived, static idx
#pragma unroll
            for (int ks = 0; ks < 4; ks++)
#pragma unroll
                for (int mt = 0; mt < 2; mt++)
                    kf[ks][mt] = *(const bf16x8*)(kbase
                        + (size_t)(32 * w + 16 * mt + l16) * KW_ + ks * 32 + q * 8);

#pragma unroll
            for (int ks = 0; ks < 4; ks++) {
                bf16x8 bf[4];
#pragma unroll
                for (int nt = 0; nt < 4; nt++)
                    bf[nt] = *(const bf16x8*)&xb[(16 * nt + l16) * PAD_ + ks * 32 + q * 8];
#pragma unroll
                for (int mt = 0; mt < 2; mt++)
#pragma unroll
                    for (int nt = 0; nt < 4; nt++)
                        cacc[tt][mt][nt] = __builtin_amdgcn_mfma_f32_16x16x32_bf16(
                            kf[ks][mt], bf[nt], cacc[tt][mt][nt], 0, 0, 0);
            }
        }
    }

    // ---- epilogue per t: gelu -> y-tile [bn][h] in buf0 -> coalesced store
#pragma unroll
    for (int tt = 0; tt < 2; tt++) {
        const int t = t0 + tt;
        __syncthreads();                           // buf free of readers
#pragma unroll
        for (int mt = 0; mt < 2; mt++) {
            int h0 = 32 * w + 16 * mt + 4 * q;
#pragma unroll
            for (int nt = 0; nt < 4; nt++) {
                unsigned short pk[4];
#pragma unroll
                for (int rr = 0; rr < 4; rr++) {
                    float v = fmaf(cacc[tt][mt][nt][rr], win[mt][rr],
                                   koff[t * H_ + h0 + rr]);
                    pk[rr] = f32_to_bf16(gelu_f(v));
                }
                *(uint2*)&x_lds[0][(16 * nt + l16) * PAD_ + h0] = *(const uint2*)pk;
            }
        }
        __syncthreads();
#pragma unroll
        for (int i = 0; i < 4; i++) {
            int c    = i * 256 + tid;
            int row  = c >> 4;
            int col8 = (c & 15) * 8;
            uint4 v = *(const uint4*)&x_lds[0][row * PAD_ + col8];
            *(uint4*)(Y + ((size_t)t * BN_ + bn0 + row) * H_ + col8) = v;
        }
    }
}

// ---------------------------------------------------------------------------
// K2: GLU GEMM + t-pool.  D[m=j][n=bn], A = W frags (VGPR-persistent, 16
// j-pairs per wave), B = Y-tile in double-buffered LDS: stage(t+1) issued
// after the barrier, before compute(t) -> next barrier's drain is covered.
// One barrier per t.  GT_=16 (736 blocks, minimal atomic flush).
// ---------------------------------------------------------------------------
__global__ __launch_bounds__(256, 4) void k_glu(
        const unsigned short* __restrict__ Y,      // [q][h]
        const unsigned short* __restrict__ Wbf,    // [256][128]
        const float* __restrict__ b_out,
        float* __restrict__ node_sum) {
    __shared__ unsigned short Yt[2][64 * PAD_];    // 2 x 17 KB

    const int tid  = threadIdx.x;
    const int w    = tid >> 6;
    const int lane = tid & 63;
    const int q    = lane >> 4;
    const int l16  = lane & 15;
    const int jg   = blockIdx.x & 1;
    const int bn0  = (blockIdx.x >> 1) * 64;
    const int tg0  = blockIdx.y * GT_;
    const int jlow = jg * 64 + w * 16;
    const int jhigh = jlow + 128;

    bf16x8 wfrag[2][4];                            // [low/high][ks]
#pragma unroll
    for (int ks = 0; ks < 4; ks++) {
        wfrag[0][ks] = *(const bf16x8*)(Wbf + (size_t)(jlow  + l16) * H_ + ks * 32 + q * 8);
        wfrag[1][ks] = *(const bf16x8*)(Wbf + (size_t)(jhigh + l16) * H_ + ks * 32 + q * 8);
    }
    float bo1[4], bo2[4];
#pragma unroll
    for (int rr = 0; rr < 4; rr++) {
        bo1[rr] = b_out[jlow  + 4 * q + rr];
        bo2[rr] = b_out[jhigh + 4 * q + rr];
    }

    f32x4 zacc[4];
#pragma unroll
    for (int nt = 0; nt < 4; nt++) zacc[nt] = (f32x4){0.f, 0.f, 0.f, 0.f};

    // prologue: stage t=tg0 into buf0 (tg0 < T_ always)
#pragma unroll
    for (int i = 0; i < 16; i++) {
        int r = w * 16 + i;
        gload_lds4(Y + ((size_t)tg0 * BN_ + bn0 + r) * H_ + lane * 2,
                   &Yt[0][r * PAD_]);
    }

    for (int g = 0; g < GT_; g++) {
        const int t = tg0 + g;
        if (t >= T_) break;                        // block-uniform
        __syncthreads();                           // drain stage(t); buf safe
        if (g + 1 < GT_ && t + 1 < T_) {           // prefetch t+1 (no wait)
#pragma unroll
            for (int i = 0; i < 16; i++) {
                int r = w * 16 + i;
                gload_lds4(Y + ((size_t)(t + 1) * BN_ + bn0 + r) * H_ + lane * 2,
                           &Yt[(g + 1) & 1][r * PAD_]);
            }
        }
        const unsigned short* buf = Yt[g & 1];

        f32x4 gacc[2][4];
#pragma unroll
        for (int mt = 0; mt < 2; mt++)
#pragma unroll
            for (int nt = 0; nt < 4; nt++) gacc[mt][nt] = (f32x4){0.f, 0.f, 0.f, 0.f};

#pragma unroll
        for (int ks = 0; ks < 4; ks++) {
            bf16x8 yf[4];
#pragma unroll
            for (int nt = 0; nt < 4; nt++)
                yf[nt] = *(const bf16x8*)&buf[(16 * nt + l16) * PAD_ + ks * 32 + q * 8];
#pragma unroll
            for (int mt = 0; mt < 2; mt++)
#pragma unroll
                for (int nt = 0; nt < 4; nt++)
                    gacc[mt][nt] = __builtin_amdgcn_mfma_f32_16x16x32_bf16(
                        wfrag[mt][ks], yf[nt], gacc[mt][nt], 0, 0, 0);
        }

#pragma unroll
        for (int nt = 0; nt < 4; nt++)
#pragma unroll
            for (int rr = 0; rr < 4; rr++) {
                float a  = gacc[0][nt][rr] + bo1[rr];
                float bs = gacc[1][nt][rr] + bo2[rr];
                float sg = 1.0f / (1.0f + __expf(-bs));
                zacc[nt][rr] += a * sg;
            }
    }

    // flush: lanes sharing a 64B line (16 consecutive j at fixed bn)
#pragma unroll
    for (int nt = 0; nt < 4; nt++)
#pragma unroll
        for (int rr = 0; rr < 4; rr++) {
            int bn = bn0 + 16 * nt + l16;
            int j  = jlow + 4 * q + rr;
            atomicAdd(&node_sum[bn * H_ + j], zacc[nt][rr]);
        }
}

// ---------------------------------------------------------------------------
// K3: logits[b] = (1/(T*N)) * sum_{n,h} node_sum[b*64+n][h] * W_cls[h] + b_cls
// ---------------------------------------------------------------------------
__global__ void k_cls(const float* __restrict__ node_sum,
                      const float* __restrict__ W_cls, const float* __restrict__ b_cls,
                      float* __restrict__ out) {
    const int b = blockIdx.x, tid = threadIdx.x;
    float s = 0.0f;
    for (int i = tid; i < N_ * H_; i += 256)
        s += node_sum[b * (N_ * H_) + i] * W_cls[i & (H_ - 1)];
    __shared__ float red[256];
    red[tid] = s;
    __syncthreads();
    for (int off = 128; off > 0; off >>= 1) {
        if (tid < off) red[tid] += red[tid + off];
        __syncthreads();
    }
    if (tid == 0) out[b] = red[0] * (1.0f / (354.0f * 64.0f)) + b_cls[0];
}

// ---------------------------------------------------------------------------
extern "C" void kernel_launch(void* const* d_in, const int* in_sizes, int n_in,
                              void* d_out, int out_size, void* d_ws, size_t ws_size,
                              hipStream_t stream) {
    const float* x      = (const float*)d_in[0];
    const float* W_in   = (const float*)d_in[1];
    const float* b_in   = (const float*)d_in[2];
    const float* log_dt = (const float*)d_in[3];
    const float* A_re   = (const float*)d_in[4];
    const float* A_im   = (const float*)d_in[5];
    const float* C_re   = (const float*)d_in[6];
    const float* C_im   = (const float*)d_in[7];
    const float* D      = (const float*)d_in[8];
    const float* W_out  = (const float*)d_in[9];
    const float* b_out  = (const float*)d_in[10];
    const float* W_cls  = (const float*)d_in[11];
    const float* b_cls  = (const float*)d_in[12];

    char* ws = (char*)d_ws;
    // [node_sum 512K][Krev 1M] contiguous -> ONE memset; rest fully written
    float*          node_sum = (float*)(ws + 0);                  //   524288 B
    unsigned short* Krev     = (unsigned short*)(ws + 524288);    //  1048576 B
    float*          koff     = (float*)(ws + 1572864);            //   181248 B
    unsigned short* xbf      = (unsigned short*)(ws + 1754112);   //   786432 B
    unsigned short* Wbf      = (unsigned short*)(ws + 2540544);   //    65536 B
    unsigned short* Y        = (unsigned short*)(ws + 2606080);   // 92798976 B

    hipMemsetAsync(ws, 0, 1572864, stream);
    k_pre<<<dim3(H_ + 96 + WB_), dim3(512), 0, stream>>>(
        log_dt, A_re, A_im, C_re, C_im, b_in, D, x, W_out, Krev, koff, xbf, Wbf);
    k_conv<<<dim3(BN_ / 64, T_ / 2), dim3(256), 0, stream>>>(
        xbf, Krev, koff, W_in, Y);
    k_glu<<<dim3(2 * BN_ / 64, NGT_), dim3(256), 0, stream>>>(
        Y, Wbf, b_out, node_sum);
    k_cls<<<dim3(B_), dim3(256), 0, stream>>>(node_sum, W_cls, b_cls, (float*)d_out);
}